// Round 8
// baseline (321.957 us; speedup 1.0000x reference)
//
#include <hip/hip_runtime.h>
#include <hip/hip_cooperative_groups.h>

namespace cg = cooperative_groups;

// ---------------------------------------------------------------------------
// Stacked 3-layer LSTM step + projection, B=256, I=512, H=1024, V=512 (fp32 io)
// Round 8: single cooperative kernel, 256 blocks x 512 thr (1 block/CU),
// 8 grid.sync()s replace 8 launch gaps. GEMM body = round-2 proven structure
// (BM=256, BN=32, A via LDS double-buffer, __syncthreads per half-tile).
// Mega phase is perfectly balanced: every block runs K-split-2 jobs of all 4
// t=0-available products (4+8+8+8 = 28 tiles/block).
// ---------------------------------------------------------------------------

typedef __attribute__((ext_vector_type(8))) short short8_t;            // 8 bf16
typedef __attribute__((ext_vector_type(8))) unsigned short ushort8_t;  // 16B
typedef __attribute__((ext_vector_type(2))) unsigned short ushort2_t;  // 4B
typedef __attribute__((ext_vector_type(4))) float f32x4;
typedef __attribute__((ext_vector_type(2))) float f32x2;

__device__ __forceinline__ unsigned short f2bf(float f) {
    union { float f; unsigned u; } v; v.f = f;
    unsigned r = v.u + 0x7FFFu + ((v.u >> 16) & 1u);   // RTNE (finite inputs)
    return (unsigned short)(r >> 16);
}

#define KT 64
#define BN 32
#define SLOT 1048576   // floats per [256][4096] partial slot

struct FusedArgs {
    const float *x,*h0,*c0,*h1,*c1,*h2,*c2;
    const float *W0,*U0,*b0,*W1,*U1,*b1,*W2,*U2,*b2,*Wp,*bp;
    float *logits,*h0n,*c0n,*h1n,*c1n,*h2n,*c2n;
    float *S;                                   // partial slots base
    unsigned short *xb,*h0b,*h1b,*h2b,*h0nb,*h1nb,*h2nb;
    int mode8;                                  // 1: 8-slot balanced schedule
};

// ---------------------------------------------------------------------------
// One GEMM job (round-2 body): Z[256][N]-partial = A[256][K-slice] @ W[slice][N]
// 512 thr, BM=256, BN=32. Wave w: rows w*32..+32, 2x2 16x16 MFMA tiles.
// A bf16 staged via 2x32KB LDS; W fp32 -> bf16 via 2x4KB LDS; ping-pong
// register prefetch; handles any nt >= 1 (odd-nt guarded).
// ---------------------------------------------------------------------------
__device__ void gemm_job(const unsigned short* __restrict__ A, const float* __restrict__ W,
                         int K, int N, int n0, int kbeg, int klen, float* __restrict__ Z,
                         unsigned short* Al0, unsigned short* Al1,
                         unsigned short* Wl0, unsigned short* Wl1)
{
    const int tid  = threadIdx.x;
    const int lane = tid & 63;
    const int w    = tid >> 6;
    const int lg   = lane >> 4;
    const int lr   = lane & 15;
    const int m0   = w * 32;
    const int nt   = klen >> 6;

    const int wkr = tid >> 3;              // W k-row within tile 0..63
    const int wcq = tid & 7;               // W float4-col 0..7

    ushort8_t paA[4], paB[4];              // ping-pong A prefetch (static idx)
    f32x4     pwA = {0,0,0,0}, pwB = {0,0,0,0};

    f32x4 acc00 = {0,0,0,0}, acc01 = {0,0,0,0}, acc10 = {0,0,0,0}, acc11 = {0,0,0,0};

    auto issue = [&](int t, ushort8_t (&pa)[4], f32x4& pw) {
        int k0 = kbeg + t * KT;
#pragma unroll
        for (int it = 0; it < 4; ++it) {
            int c = tid + it * 512;        // 2048 chunks = 256 rows x 8
            int row = c >> 3, cc = c & 7;
            pa[it] = *(const ushort8_t*)(A + (size_t)row * K + k0 + cc * 8);
        }
        pw = *(const f32x4*)(W + (size_t)(k0 + wkr) * N + n0 + wcq * 4);
    };

    auto stage = [&](ushort8_t (&pa)[4], f32x4& pw,
                     unsigned short* al, unsigned short* wl) {
#pragma unroll
        for (int it = 0; it < 4; ++it) {
            int c = tid + it * 512;
            int row = c >> 3, cc = c & 7;
            *(ushort8_t*)(al + row * KT + ((cc ^ (row & 7)) << 3)) = pa[it];
        }
        unsigned short bs[4] = { f2bf(pw[0]), f2bf(pw[1]), f2bf(pw[2]), f2bf(pw[3]) };
        int kch = wkr >> 3, kwi = wkr & 7;
#pragma unroll
        for (int j = 0; j < 4; ++j) {
            int n = wcq * 4 + j;           // transposed: Wl[n][k]
            wl[n * KT + ((kch ^ (n & 7)) << 3) + kwi] = bs[j];
        }
    };

    auto compute = [&](const unsigned short* al, const unsigned short* wl) {
#pragma unroll
        for (int ks = 0; ks < 2; ++ks) {
            int ch = ks * 4 + lg;
            int nb0 = lr, nb1 = 16 + lr;
            short8_t b0f = *(const short8_t*)(wl + nb0 * KT + ((ch ^ (nb0 & 7)) << 3));
            short8_t b1f = *(const short8_t*)(wl + nb1 * KT + ((ch ^ (nb1 & 7)) << 3));
            int r0 = m0 + lr, r1 = m0 + 16 + lr;
            short8_t a0f = *(const short8_t*)(al + r0 * KT + ((ch ^ (r0 & 7)) << 3));
            short8_t a1f = *(const short8_t*)(al + r1 * KT + ((ch ^ (r1 & 7)) << 3));
            acc00 = __builtin_amdgcn_mfma_f32_16x16x32_bf16(a0f, b0f, acc00, 0, 0, 0);
            acc01 = __builtin_amdgcn_mfma_f32_16x16x32_bf16(a0f, b1f, acc01, 0, 0, 0);
            acc10 = __builtin_amdgcn_mfma_f32_16x16x32_bf16(a1f, b0f, acc10, 0, 0, 0);
            acc11 = __builtin_amdgcn_mfma_f32_16x16x32_bf16(a1f, b1f, acc11, 0, 0, 0);
        }
    };

    // prologue
    issue(0, paA, pwA);
    stage(paA, pwA, Al0, Wl0);
    if (1 < nt) issue(1, paB, pwB);
    __syncthreads();                       // publish buf0

    for (int t = 0; t < nt; t += 2) {
        if (t + 2 < nt) issue(t + 2, paA, pwA);
        if (t + 1 < nt) stage(paB, pwB, Al1, Wl1);
        compute(Al0, Wl0);
        __syncthreads();
        if (t + 1 < nt) {
            if (t + 3 < nt) issue(t + 3, paB, pwB);
            if (t + 2 < nt) stage(paA, pwA, Al0, Wl0);
            compute(Al1, Wl1);
            __syncthreads();
        }
    }

    // epilogue: D mapping col=lane&15, row=4*(lane>>4)+reg  [m89/m91]
#pragma unroll
    for (int r = 0; r < 4; ++r) {
        int ma = m0 + lg * 4 + r;
        int mb = ma + 16;
        Z[(size_t)ma * N + n0 + lr]      = acc00[r];
        Z[(size_t)ma * N + n0 + 16 + lr] = acc01[r];
        Z[(size_t)mb * N + n0 + lr]      = acc10[r];
        Z[(size_t)mb * N + n0 + 16 + lr] = acc11[r];
    }
}

// ---------------------------------------------------------------------------
// Phase bodies (shared between fused kernel and fallback wrappers)
// ---------------------------------------------------------------------------
__device__ void phase_pack(const FusedArgs& a, int t)
{
    if (t >= 114688) return;               // 917504 floats / 8
    const float* src; unsigned short* dst; int u;
    if (t < 16384)      { src = a.x;  dst = a.xb;  u = t; }
    else if (t < 49152) { src = a.h0; dst = a.h0b; u = t - 16384; }
    else if (t < 81920) { src = a.h1; dst = a.h1b; u = t - 49152; }
    else                { src = a.h2; dst = a.h2b; u = t - 81920; }
    f32x4 v0 = *(const f32x4*)(src + (size_t)u * 8);
    f32x4 v1 = *(const f32x4*)(src + (size_t)u * 8 + 4);
    ushort8_t o;
#pragma unroll
    for (int j = 0; j < 4; ++j) { o[j] = f2bf(v0[j]); o[4 + j] = f2bf(v1[j]); }
    *(ushort8_t*)(dst + (size_t)u * 8) = o;
}

__device__ void phase_p2(const FusedArgs& a, int bid,
                         unsigned short* Al0, unsigned short* Al1,
                         unsigned short* Wl0, unsigned short* Wl1)
{
    if (a.mode8) {                         // balanced: 4 split-2 jobs/block
        int ns = bid >> 1, kb = bid & 1, n0 = ns * BN;
        gemm_job(a.xb,  a.W0, 512,  4096, n0, kb * 256, 256, a.S + (size_t)(0 + kb) * SLOT, Al0, Al1, Wl0, Wl1);
        gemm_job(a.h0b, a.U0, 1024, 4096, n0, kb * 512, 512, a.S + (size_t)(2 + kb) * SLOT, Al0, Al1, Wl0, Wl1);
        gemm_job(a.h1b, a.U1, 1024, 4096, n0, kb * 512, 512, a.S + (size_t)(4 + kb) * SLOT, Al0, Al1, Wl0, Wl1);
        gemm_job(a.h2b, a.U2, 1024, 4096, n0, kb * 512, 512, a.S + (size_t)(6 + kb) * SLOT, Al0, Al1, Wl0, Wl1);
    } else {                               // 4-slot: 2 full-K jobs/block
        if (bid < 128) {
            int n0 = bid * BN;
            gemm_job(a.xb,  a.W0, 512,  4096, n0, 0, 512,  a.S + (size_t)0 * SLOT, Al0, Al1, Wl0, Wl1);
            gemm_job(a.h1b, a.U1, 1024, 4096, n0, 0, 1024, a.S + (size_t)2 * SLOT, Al0, Al1, Wl0, Wl1);
        } else {
            int n0 = (bid - 128) * BN;
            gemm_job(a.h0b, a.U0, 1024, 4096, n0, 0, 1024, a.S + (size_t)1 * SLOT, Al0, Al1, Wl0, Wl1);
            gemm_job(a.h2b, a.U2, 1024, 4096, n0, 0, 1024, a.S + (size_t)3 * SLOT, Al0, Al1, Wl0, Wl1);
        }
    }
}

__device__ void phase_w(const FusedArgs& a, int which, int bid,
                        unsigned short* Al0, unsigned short* Al1,
                        unsigned short* Wl0, unsigned short* Wl1)
{
    const unsigned short* A = (which == 1) ? a.h0nb : a.h1nb;
    const float*          W = (which == 1) ? a.W1   : a.W2;
    int ns = bid >> 1, kb = bid & 1;
    gemm_job(A, W, 1024, 4096, ns * BN, kb * 512, 512, a.S + (size_t)kb * SLOT, Al0, Al1, Wl0, Wl1);
}

__device__ void phase_proj(const FusedArgs& a, int bid,
                           unsigned short* Al0, unsigned short* Al1,
                           unsigned short* Wl0, unsigned short* Wl1)
{
    int ns = bid >> 4, kb = bid & 15;      // 16 strips x K-split-16, nt=1
    gemm_job(a.h2nb, a.Wp, 1024, 512, ns * BN, kb * 64, 64,
             a.S + (size_t)kb * 131072, Al0, Al1, Wl0, Wl1);
}

__device__ void gates_phase(const float* __restrict__ pz1, int n1,
                            const float* __restrict__ pz2, int n2,
                            const float* __restrict__ bias, const float* __restrict__ c_old,
                            float* __restrict__ h_out, float* __restrict__ c_out,
                            unsigned short* __restrict__ h_bf, int t)
{
    int b = t >> 9;                        // 131072 threads x 2 elems
    int n = (t & 511) << 1;
    f32x2 iv = *(const f32x2*)(bias + n);
    f32x2 fv = *(const f32x2*)(bias + 1024 + n);
    f32x2 gv = *(const f32x2*)(bias + 2048 + n);
    f32x2 ov = *(const f32x2*)(bias + 3072 + n);
    for (int i = 0; i < n1; ++i) {
        const float* z = pz1 + (size_t)i * SLOT + (size_t)b * 4096;
        iv += *(const f32x2*)(z + n);        fv += *(const f32x2*)(z + 1024 + n);
        gv += *(const f32x2*)(z + 2048 + n); ov += *(const f32x2*)(z + 3072 + n);
    }
    for (int i = 0; i < n2; ++i) {
        const float* z = pz2 + (size_t)i * SLOT + (size_t)b * 4096;
        iv += *(const f32x2*)(z + n);        fv += *(const f32x2*)(z + 1024 + n);
        gv += *(const f32x2*)(z + 2048 + n); ov += *(const f32x2*)(z + 3072 + n);
    }
    f32x2 cv = *(const f32x2*)(c_old + (size_t)b * 1024 + n);
    f32x2 hn, cn; ushort2_t hb;
#pragma unroll
    for (int j = 0; j < 2; ++j) {
        float ii = 1.f / (1.f + __expf(-iv[j]));
        float ff = 1.f / (1.f + __expf(-fv[j]));
        float gg = tanhf(gv[j]);
        float oo = 1.f / (1.f + __expf(-ov[j]));
        float c2 = ff * cv[j] + ii * gg;
        cn[j] = c2;
        float h2 = oo * tanhf(c2);
        hn[j] = h2;
        hb[j] = f2bf(h2);
    }
    *(f32x2*)(c_out + (size_t)b * 1024 + n) = cn;
    *(f32x2*)(h_out + (size_t)b * 1024 + n) = hn;
    *(ushort2_t*)(h_bf + (size_t)b * 1024 + n) = hb;
}

__device__ void phase_final(const FusedArgs& a, int t)
{
    float v = a.bp[t & 511];               // 131072 = 256x512 logits exactly
    for (int kb = 0; kb < 16; ++kb)
        v += a.S[(size_t)kb * 131072 + t];
    a.logits[t] = v;
}

// ---------------------------------------------------------------------------
// The fused cooperative kernel
// ---------------------------------------------------------------------------
__global__ __launch_bounds__(512, 2)
void k_fused(FusedArgs a)
{
    __shared__ unsigned short Al0[256 * KT];   // 32 KB
    __shared__ unsigned short Al1[256 * KT];   // 32 KB
    __shared__ unsigned short Wl0[BN * KT];    // 4 KB
    __shared__ unsigned short Wl1[BN * KT];    // 4 KB

    cg::grid_group grid = cg::this_grid();
    const int bid = blockIdx.x;
    const int gt  = bid * 512 + threadIdx.x;

    phase_pack(a, gt);
    grid.sync();
    phase_p2(a, bid, Al0, Al1, Wl0, Wl1);
    grid.sync();
    gates_phase(a.S, a.mode8 ? 4 : 2, nullptr, 0, a.b0, a.c0, a.h0n, a.c0n, a.h0nb, gt);
    grid.sync();
    phase_w(a, 1, bid, Al0, Al1, Wl0, Wl1);
    grid.sync();
    gates_phase(a.S, 2, a.S + (size_t)(a.mode8 ? 4 : 2) * SLOT, a.mode8 ? 2 : 1,
                a.b1, a.c1, a.h1n, a.c1n, a.h1nb, gt);
    grid.sync();
    phase_w(a, 2, bid, Al0, Al1, Wl0, Wl1);
    grid.sync();
    gates_phase(a.S, 2, a.S + (size_t)(a.mode8 ? 6 : 3) * SLOT, a.mode8 ? 2 : 1,
                a.b2, a.c2, a.h2n, a.c2n, a.h2nb, gt);
    grid.sync();
    phase_proj(a, bid, Al0, Al1, Wl0, Wl1);
    grid.sync();
    phase_final(a, gt);
}

// ---------------------------------------------------------------------------
// Fallback wrappers (plain launches) if cooperative enqueue is rejected
// ---------------------------------------------------------------------------
__global__ __launch_bounds__(512, 2) void k_pack(FusedArgs a)
{ phase_pack(a, blockIdx.x * 512 + threadIdx.x); }

__global__ __launch_bounds__(512, 2) void k_p2(FusedArgs a)
{
    __shared__ unsigned short Al0[256 * KT], Al1[256 * KT], Wl0[BN * KT], Wl1[BN * KT];
    phase_p2(a, blockIdx.x, Al0, Al1, Wl0, Wl1);
}
__global__ __launch_bounds__(512, 2) void k_w(FusedArgs a, int which)
{
    __shared__ unsigned short Al0[256 * KT], Al1[256 * KT], Wl0[BN * KT], Wl1[BN * KT];
    phase_w(a, which, blockIdx.x, Al0, Al1, Wl0, Wl1);
}
__global__ __launch_bounds__(512, 2) void k_proj(FusedArgs a)
{
    __shared__ unsigned short Al0[256 * KT], Al1[256 * KT], Wl0[BN * KT], Wl1[BN * KT];
    phase_proj(a, blockIdx.x, Al0, Al1, Wl0, Wl1);
}
__global__ __launch_bounds__(512, 2) void k_gates(FusedArgs a, int which)
{
    int gt = blockIdx.x * 512 + threadIdx.x;
    if (which == 0)
        gates_phase(a.S, a.mode8 ? 4 : 2, nullptr, 0, a.b0, a.c0, a.h0n, a.c0n, a.h0nb, gt);
    else if (which == 1)
        gates_phase(a.S, 2, a.S + (size_t)(a.mode8 ? 4 : 2) * SLOT, a.mode8 ? 2 : 1,
                    a.b1, a.c1, a.h1n, a.c1n, a.h1nb, gt);
    else
        gates_phase(a.S, 2, a.S + (size_t)(a.mode8 ? 6 : 3) * SLOT, a.mode8 ? 2 : 1,
                    a.b2, a.c2, a.h2n, a.c2n, a.h2nb, gt);
}
__global__ __launch_bounds__(512, 2) void k_final(FusedArgs a)
{ phase_final(a, blockIdx.x * 512 + threadIdx.x); }

// ---------------------------------------------------------------------------
extern "C" void kernel_launch(void* const* d_in, const int* in_sizes, int n_in,
                              void* d_out, int out_size, void* d_ws, size_t ws_size,
                              hipStream_t stream)
{
    FusedArgs a;
    a.x  = (const float*)d_in[0];
    a.h0 = (const float*)d_in[1];
    a.c0 = (const float*)d_in[2];
    a.h1 = (const float*)d_in[3];
    a.c1 = (const float*)d_in[4];
    a.h2 = (const float*)d_in[5];
    a.c2 = (const float*)d_in[6];
    a.W0 = (const float*)d_in[7];
    a.U0 = (const float*)d_in[8];
    a.b0 = (const float*)d_in[9];
    a.W1 = (const float*)d_in[10];
    a.U1 = (const float*)d_in[11];
    a.b1 = (const float*)d_in[12];
    a.W2 = (const float*)d_in[13];
    a.U2 = (const float*)d_in[14];
    a.b2 = (const float*)d_in[15];
    a.Wp = (const float*)d_in[16];
    a.bp = (const float*)d_in[17];

    float* out = (float*)d_out;
    a.logits = out;
    a.h0n = out + 131072;
    a.c0n = a.h0n + 262144;
    a.h1n = a.c0n + 262144;
    a.c1n = a.h1n + 262144;
    a.h2n = a.c1n + 262144;
    a.c2n = a.h2n + 262144;

    const size_t SLOTB = 4194304ull;                 // 4 MB per slot
    const size_t bfB   = 262144ull + 6ull * 524288ull;
    a.mode8 = (ws_size >= 8 * SLOTB + bfB) ? 1 : 0;
    const int nsl = a.mode8 ? 8 : 4;

    a.S = (float*)d_ws;
    unsigned short* bufs = (unsigned short*)((char*)d_ws + (size_t)nsl * SLOTB);
    a.xb   = bufs;
    a.h0b  = bufs   + 131072;
    a.h1b  = a.h0b  + 262144;
    a.h2b  = a.h1b  + 262144;
    a.h0nb = a.h2b  + 262144;
    a.h1nb = a.h0nb + 262144;
    a.h2nb = a.h1nb + 262144;

    void* kargs[] = { (void*)&a };
    hipError_t e = hipLaunchCooperativeKernel((const void*)k_fused,
                                              dim3(256), dim3(512), kargs, 0, stream);
    if (e != hipSuccess) {
        (void)hipGetLastError();                     // clear, use plain launches
        k_pack <<<256, 512, 0, stream>>>(a);
        k_p2   <<<256, 512, 0, stream>>>(a);
        k_gates<<<256, 512, 0, stream>>>(a, 0);
        k_w    <<<256, 512, 0, stream>>>(a, 1);
        k_gates<<<256, 512, 0, stream>>>(a, 1);
        k_w    <<<256, 512, 0, stream>>>(a, 2);
        k_gates<<<256, 512, 0, stream>>>(a, 2);
        k_proj <<<256, 512, 0, stream>>>(a);
        k_final<<<256, 512, 0, stream>>>(a);
    }
}

// Round 9
// 77.565 us; speedup vs baseline: 4.1508x; 4.1508x over previous
//
#include <hip/hip_runtime.h>

// ---------------------------------------------------------------------------
// Stacked 3-layer LSTM step + projection, B=256, I=512, H=1024, V=512 (fp32 io)
// Round 9 = round-2 proven GEMM body (best: 75.8us) + two minimal changes:
//   (1) counted-vmcnt barrier: s_waitcnt lgkmcnt(0) + s_barrier instead of
//       __syncthreads() -> prefetch global loads stay in flight across
//       barriers (T4), removing the per-phase vmcnt(0) drain.
//   (2) 2 blocks/CU: __launch_bounds__(512,4) + K-split-4 (grid 512) so a
//       co-resident block covers residual barrier stalls.
// Launch graph (9 nodes, round-2): pack -> L0 gemm -> gates0 -> L1 gemm ->
// gates1 -> L2 gemm -> gates2 -> proj gemm -> finalize.
// ---------------------------------------------------------------------------

typedef __attribute__((ext_vector_type(8))) short short8_t;            // 8 bf16 (MFMA frag)
typedef __attribute__((ext_vector_type(8))) unsigned short ushort8_t;  // 16B ld/st
typedef __attribute__((ext_vector_type(4))) unsigned short ushort4_t;  // 8B st
typedef __attribute__((ext_vector_type(4))) float f32x4;               // MFMA acc / 16B ld

__device__ __forceinline__ unsigned short f2bf(float f) {
    union { float f; unsigned u; } v; v.f = f;
    unsigned r = v.u + 0x7FFFu + ((v.u >> 16) & 1u);   // RTNE (finite inputs)
    return (unsigned short)(r >> 16);
}

#define KT 64
#define BN 32
#define SLOT 1048576   // floats per [256][4096] partial slot

// ---------------------------------------------------------------------------
// zp[kb][256][N] = A[256][K-slice kb] @ W[K-slice kb][N]
// A = concat(A1[256][K1], A2[256][Ktot-K1]) bf16; W = concat(W1,W2) fp32 rows.
// Block: 512 thr (8 waves), BM=256 (full M), BN=32. grid = (N/32) << lgs.
// Wave w: rows w*32..+32, 2x2 16x16 MFMA tiles. A+W via LDS double buffer,
// ping-pong register prefetch, counted-vmcnt barriers.
// ---------------------------------------------------------------------------
__global__ __launch_bounds__(512, 4)
void gemm32(const unsigned short* __restrict__ A1, const float* __restrict__ W1, int K1,
            const unsigned short* __restrict__ A2, const float* __restrict__ W2,
            int N, int Ktot, int lgs, float* __restrict__ zp)
{
    __shared__ unsigned short Al0[256 * KT];   // 32 KB  (16B-chunk XOR swizzled)
    __shared__ unsigned short Al1[256 * KT];   // 32 KB
    __shared__ unsigned short Wl0[BN * KT];    // 4 KB   ([n][k] transposed, swizzled)
    __shared__ unsigned short Wl1[BN * KT];    // 4 KB

    const int tid  = threadIdx.x;
    const int lane = tid & 63;
    const int w    = tid >> 6;
    const int lg   = lane >> 4;
    const int lr   = lane & 15;
    const int nsplit = 1 << lgs;
    const int kb   = blockIdx.x & (nsplit - 1);
    const int ns   = blockIdx.x >> lgs;
    const int n0   = ns * BN;
    const int m0   = w * 32;
    const int klen = Ktot >> lgs;
    const int kbeg = kb * klen;
    const int nt   = klen >> 6;            // even for all shapes used

    const int wkr = tid >> 3;              // W k-row within tile 0..63
    const int wcq = tid & 7;               // W float4-col 0..7

    ushort8_t paA[4], paB[4];              // ping-pong A prefetch (static idx)
    f32x4     pwA = {0,0,0,0}, pwB = {0,0,0,0};

    f32x4 acc00 = {0,0,0,0}, acc01 = {0,0,0,0}, acc10 = {0,0,0,0}, acc11 = {0,0,0,0};

    auto issue = [&](int t, ushort8_t (&pa)[4], f32x4& pw) {
        int k0 = kbeg + t * KT;
        const unsigned short* A; const float* Wm; int ldA, krel;
        if (k0 < K1) { A = A1; Wm = W1; ldA = K1;        krel = k0; }
        else         { A = A2; Wm = W2; ldA = Ktot - K1; krel = k0 - K1; }
#pragma unroll
        for (int it = 0; it < 4; ++it) {
            int c = tid + it * 512;        // 2048 chunks = 256 rows x 8
            int row = c >> 3, cc = c & 7;
            pa[it] = *(const ushort8_t*)(A + (size_t)row * ldA + krel + cc * 8);
        }
        pw = *(const f32x4*)(Wm + (size_t)(krel + wkr) * N + n0 + wcq * 4);
    };

    auto stage = [&](ushort8_t (&pa)[4], f32x4& pw,
                     unsigned short* al, unsigned short* wl) {
#pragma unroll
        for (int it = 0; it < 4; ++it) {
            int c = tid + it * 512;
            int row = c >> 3, cc = c & 7;
            *(ushort8_t*)(al + row * KT + ((cc ^ (row & 7)) << 3)) = pa[it];
        }
        unsigned short bs[4] = { f2bf(pw[0]), f2bf(pw[1]), f2bf(pw[2]), f2bf(pw[3]) };
        int kch = wkr >> 3, kwi = wkr & 7;
#pragma unroll
        for (int j = 0; j < 4; ++j) {
            int n = wcq * 4 + j;           // transposed: Wl[n][k]
            wl[n * KT + ((kch ^ (n & 7)) << 3) + kwi] = bs[j];
        }
    };

    auto compute = [&](const unsigned short* al, const unsigned short* wl) {
#pragma unroll
        for (int ks = 0; ks < 2; ++ks) {
            int ch = ks * 4 + lg;
            int nb0 = lr, nb1 = 16 + lr;
            short8_t b0f = *(const short8_t*)(wl + nb0 * KT + ((ch ^ (nb0 & 7)) << 3));
            short8_t b1f = *(const short8_t*)(wl + nb1 * KT + ((ch ^ (nb1 & 7)) << 3));
            int r0 = m0 + lr, r1 = m0 + 16 + lr;
            short8_t a0f = *(const short8_t*)(al + r0 * KT + ((ch ^ (r0 & 7)) << 3));
            short8_t a1f = *(const short8_t*)(al + r1 * KT + ((ch ^ (r1 & 7)) << 3));
            acc00 = __builtin_amdgcn_mfma_f32_16x16x32_bf16(a0f, b0f, acc00, 0, 0, 0);
            acc01 = __builtin_amdgcn_mfma_f32_16x16x32_bf16(a0f, b1f, acc01, 0, 0, 0);
            acc10 = __builtin_amdgcn_mfma_f32_16x16x32_bf16(a1f, b0f, acc10, 0, 0, 0);
            acc11 = __builtin_amdgcn_mfma_f32_16x16x32_bf16(a1f, b1f, acc11, 0, 0, 0);
        }
    };

    // counted-vmcnt barrier: drain LDS ops only; global prefetch stays in
    // flight (compiler inserts its own counted vmcnt waits at register use).
#define BAR() do { asm volatile("s_waitcnt lgkmcnt(0)" ::: "memory"); \
                   __builtin_amdgcn_s_barrier(); } while (0)

    // prologue
    issue(0, paA, pwA);
    stage(paA, pwA, Al0, Wl0);
    if (1 < nt) issue(1, paB, pwB);
    BAR();                                 // publish buf0

    for (int t = 0; t < nt; t += 2) {
        if (t + 2 < nt) issue(t + 2, paA, pwA);
        if (t + 1 < nt) stage(paB, pwB, Al1, Wl1);
        compute(Al0, Wl0);                 // tile t
        BAR();                             // publish buf1
        if (t + 1 < nt) {
            if (t + 3 < nt) issue(t + 3, paB, pwB);
            if (t + 2 < nt) stage(paA, pwA, Al0, Wl0);
            compute(Al1, Wl1);             // tile t+1
            BAR();                         // publish buf0
        }
    }
#undef BAR

    // epilogue: D mapping col=lane&15, row=4*(lane>>4)+reg  [m89/m91]
    float* zrow = zp + (size_t)kb * 256 * N;
#pragma unroll
    for (int r = 0; r < 4; ++r) {
        int ma = m0 + lg * 4 + r;
        int mb = ma + 16;
        zrow[(size_t)ma * N + n0 + lr]      = acc00[r];
        zrow[(size_t)ma * N + n0 + 16 + lr] = acc01[r];
        zrow[(size_t)mb * N + n0 + lr]      = acc10[r];
        zrow[(size_t)mb * N + n0 + 16 + lr] = acc11[r];
    }
}

// ---------------------------------------------------------------------------
// Gates: z = sum_kb zp[kb] + bias -> h_new, c_new (fp32) + h_new bf16
// ---------------------------------------------------------------------------
__global__ __launch_bounds__(256)
void lstm_gates(const float* __restrict__ zp, int nsplit,
                const float* __restrict__ bias, const float* __restrict__ c_old,
                float* __restrict__ h_out, float* __restrict__ c_out,
                unsigned short* __restrict__ h_bf)
{
    int t = blockIdx.x * 256 + threadIdx.x;   // 65536 threads, 4 elems each
    int b = t >> 8;
    int n = (t & 255) << 2;
    f32x4 iv = *(const f32x4*)(bias + n);
    f32x4 fv = *(const f32x4*)(bias + 1024 + n);
    f32x4 gv = *(const f32x4*)(bias + 2048 + n);
    f32x4 ov = *(const f32x4*)(bias + 3072 + n);
    for (int kb = 0; kb < nsplit; ++kb) {
        const float* z = zp + (size_t)kb * SLOT + (size_t)b * 4096;
        iv += *(const f32x4*)(z + n);
        fv += *(const f32x4*)(z + 1024 + n);
        gv += *(const f32x4*)(z + 2048 + n);
        ov += *(const f32x4*)(z + 3072 + n);
    }
    f32x4 cv = *(const f32x4*)(c_old + (size_t)b * 1024 + n);

    f32x4 hn, cn;
    ushort4_t hb;
#pragma unroll
    for (int j = 0; j < 4; ++j) {
        float ii = 1.f / (1.f + __expf(-iv[j]));
        float ff = 1.f / (1.f + __expf(-fv[j]));
        float gg = tanhf(gv[j]);
        float oo = 1.f / (1.f + __expf(-ov[j]));
        float c2 = ff * cv[j] + ii * gg;
        cn[j] = c2;
        float h2 = oo * tanhf(c2);
        hn[j] = h2;
        hb[j] = f2bf(h2);
    }
    *(f32x4*)(c_out + (size_t)b * 1024 + n) = cn;
    *(f32x4*)(h_out + (size_t)b * 1024 + n) = hn;
    *(ushort4_t*)(h_bf + (size_t)b * 1024 + n) = hb;
}

// ---------------------------------------------------------------------------
// logits = sum_kb zp[kb] + bp   (proj partial reduce), partial stride 131072
// ---------------------------------------------------------------------------
__global__ __launch_bounds__(256)
void finalize_proj(const float* __restrict__ zp, int nsplit,
                   const float* __restrict__ bp, float* __restrict__ logits)
{
    int t = blockIdx.x * 256 + threadIdx.x;   // 32768 threads x 4 elems
    int i = t * 4;
    f32x4 v = *(const f32x4*)(bp + (i & 511));
    for (int kb = 0; kb < nsplit; ++kb)
        v += *(const f32x4*)(zp + (size_t)kb * 131072 + i);
    *(f32x4*)(logits + i) = v;
}

// ---------------------------------------------------------------------------
// Pack fp32 -> bf16 for x, h0, h1, h2
// ---------------------------------------------------------------------------
__global__ __launch_bounds__(256)
void pack_bf16(const float* __restrict__ x,  const float* __restrict__ h0,
               const float* __restrict__ h1, const float* __restrict__ h2,
               unsigned short* __restrict__ xb,  unsigned short* __restrict__ h0b,
               unsigned short* __restrict__ h1b, unsigned short* __restrict__ h2b)
{
    int t = blockIdx.x * 256 + threadIdx.x;
    const float* src; unsigned short* dst; int off;
    if (t < 32768)       { src = x;  dst = xb;  off = t; }
    else if (t < 98304)  { src = h0; dst = h0b; off = t - 32768; }
    else if (t < 163840) { src = h1; dst = h1b; off = t - 98304; }
    else                 { src = h2; dst = h2b; off = t - 163840; }
    f32x4 v = *(const f32x4*)(src + (size_t)off * 4);
    ushort4_t o;
#pragma unroll
    for (int j = 0; j < 4; ++j) o[j] = f2bf(v[j]);
    *(ushort4_t*)(dst + (size_t)off * 4) = o;
}

// ---------------------------------------------------------------------------
extern "C" void kernel_launch(void* const* d_in, const int* in_sizes, int n_in,
                              void* d_out, int out_size, void* d_ws, size_t ws_size,
                              hipStream_t stream)
{
    const float* x  = (const float*)d_in[0];
    const float* h0 = (const float*)d_in[1];
    const float* c0 = (const float*)d_in[2];
    const float* h1 = (const float*)d_in[3];
    const float* c1 = (const float*)d_in[4];
    const float* h2 = (const float*)d_in[5];
    const float* c2 = (const float*)d_in[6];
    const float* W0 = (const float*)d_in[7];
    const float* U0 = (const float*)d_in[8];
    const float* b0 = (const float*)d_in[9];
    const float* W1 = (const float*)d_in[10];
    const float* U1 = (const float*)d_in[11];
    const float* b1 = (const float*)d_in[12];
    const float* W2 = (const float*)d_in[13];
    const float* U2 = (const float*)d_in[14];
    const float* b2 = (const float*)d_in[15];
    const float* Wp = (const float*)d_in[16];
    const float* bp = (const float*)d_in[17];

    float* out    = (float*)d_out;
    float* logits = out;                    // [256,512]
    float* h0n = out + 131072;              // [256,1024] each below
    float* c0n = h0n + 262144;
    float* h1n = c0n + 262144;
    float* c1n = h1n + 262144;
    float* h2n = c1n + 262144;
    float* c2n = h2n + 262144;

    // K-split-4 needs: zp 16MB + xb 256KB + 6x h-bf16 512KB = 20,185,088 B
    const size_t need4 = 16777216ull + 262144ull + 6ull * 524288ull;
    const size_t need2 = 8388608ull  + 262144ull + 6ull * 524288ull;
    const int lgs    = (ws_size >= need4) ? 2 : (ws_size >= need2) ? 1 : 0;
    const int nsplit = 1 << lgs;
    const size_t zbytes = (size_t)nsplit * 4194304ull;

    char* ws = (char*)d_ws;
    float*          zp   = (float*)ws;                         // [nsplit][256][4096]
    unsigned short* xb   = (unsigned short*)(ws + zbytes);
    unsigned short* h0b  = (unsigned short*)(ws + zbytes + 262144);
    unsigned short* h1b  = (unsigned short*)(ws + zbytes + 262144 + 524288);
    unsigned short* h2b  = (unsigned short*)(ws + zbytes + 262144 + 2*524288);
    unsigned short* h0nb = (unsigned short*)(ws + zbytes + 262144 + 3*524288);
    unsigned short* h1nb = (unsigned short*)(ws + zbytes + 262144 + 4*524288);
    unsigned short* h2nb = (unsigned short*)(ws + zbytes + 262144 + 5*524288);

    pack_bf16<<<896, 256, 0, stream>>>(x, h0, h1, h2, xb, h0b, h1b, h2b);

    // layer 0: z = x@W0 + h0@U0   (K1=512, Ktot=1536, klen=384 -> nt=6)
    gemm32<<<128 * nsplit, 512, 0, stream>>>(xb, W0, 512, h0b, U0, 4096, 1536, lgs, zp);
    lstm_gates<<<256, 256, 0, stream>>>(zp, nsplit, b0, c0, h0n, c0n, h0nb);

    // layer 1: z = h0n@W1 + h1@U1  (K1=1024, Ktot=2048, klen=512 -> nt=8)
    gemm32<<<128 * nsplit, 512, 0, stream>>>(h0nb, W1, 1024, h1b, U1, 4096, 2048, lgs, zp);
    lstm_gates<<<256, 256, 0, stream>>>(zp, nsplit, b1, c1, h1n, c1n, h1nb);

    // layer 2: z = h1n@W2 + h2@U2  (K1=1024, Ktot=2048)
    gemm32<<<128 * nsplit, 512, 0, stream>>>(h1nb, W2, 1024, h2b, U2, 4096, 2048, lgs, zp);
    lstm_gates<<<256, 256, 0, stream>>>(zp, nsplit, b2, c2, h2n, c2n, h2nb);

    // projection: logits = h2n@Wp + bp  (K=1024, N=512; K-split-8 -> nt=2)
    gemm32<<<16 * 8, 512, 0, stream>>>(h2nb, Wp, 1024,
                                       (const unsigned short*)nullptr,
                                       (const float*)nullptr, 512, 1024, 3, zp);
    finalize_proj<<<128, 256, 0, stream>>>(zp, 8, bp, logits);
}